// Round 3
// baseline (446.004 us; speedup 1.0000x reference)
//
#include <hip/hip_runtime.h>
#include <hip/hip_bf16.h>
#include <stdint.h>
#include <type_traits>

// Problem constants (reference: N=16384, F=1024, B=512)
#define N_ROWS 16384
#define F_DIM  1024
#define B_DIM  512
#define K_DIM  1536   // F + B
#define G_DIM  4096   // 4*F
#define NT     24     // K_DIM / 64 K-tiles
#define CB_STR 68     // padded fp32 stride for epilogue LDS tile (68%32==4 -> 2-way max)

typedef __bf16 v8bf __attribute__((ext_vector_type(8)));
typedef float  v4f  __attribute__((ext_vector_type(4)));

typedef const void __attribute__((address_space(1)))* gptr1;
typedef void       __attribute__((address_space(3)))* lptr3;

__device__ __forceinline__ unsigned short f2bf(float x) {
    union { float f; unsigned int u; } c; c.f = x;
    unsigned int u = c.u;
    return (unsigned short)((u + 0x7FFFu + ((u >> 16) & 1u)) >> 16);  // RNE; inputs finite
}

__device__ __forceinline__ float sigmoidf_fast(float x) {
    return 1.f / (1.f + __expf(-x));
}
__device__ __forceinline__ float tanhf_fast(float x) {
    return 1.f - 2.f / (__expf(2.f * x) + 1.f);   // saturates correctly at +/-1
}

// ---------------------------------------------------------------------------
// Merged pack kernel:
//   blocks [0, N_ROWS)           : A = bf16([h_prev | behavior]) row-major
//   blocks [N_ROWS, N_ROWS+G_DIM): W' = bf16 gate-interleaved [Wh | Wx], b'
// ---------------------------------------------------------------------------
__global__ void pack_all(const float* __restrict__ behavior,
                         const float* __restrict__ h_prev,
                         const float* __restrict__ Wh,
                         const float* __restrict__ Wx,
                         const float* __restrict__ b,
                         unsigned short* __restrict__ A,
                         unsigned short* __restrict__ W,
                         float* __restrict__ bperm) {
    const int blk = blockIdx.x;
    const int col = threadIdx.x * 8;              // 0..1528, never straddles 1024
    const float* src;
    unsigned short* dst;
    if (blk < N_ROWS) {
        src = (col < F_DIM) ? h_prev + (long)blk * F_DIM + col
                            : behavior + (long)blk * B_DIM + (col - F_DIM);
        dst = A + (long)blk * K_DIM + col;
    } else {
        const int gp   = blk - N_ROWS;
        const int gate = gp & 3;
        const int f    = gp >> 2;
        const int g    = gate * F_DIM + f;        // original row in Wh/Wx
        src = (col < F_DIM) ? Wh + (long)g * F_DIM + col
                            : Wx + (long)g * B_DIM + (col - F_DIM);
        dst = W + (long)gp * K_DIM + col;
        if (threadIdx.x == 0) bperm[gp] = b[g];
    }
    float4 lo = *(const float4*)src;
    float4 hi = *(const float4*)(src + 4);
    union { unsigned short u[8]; int4 v; } p;
    p.u[0] = f2bf(lo.x); p.u[1] = f2bf(lo.y); p.u[2] = f2bf(lo.z); p.u[3] = f2bf(lo.w);
    p.u[4] = f2bf(hi.x); p.u[5] = f2bf(hi.y); p.u[6] = f2bf(hi.z); p.u[7] = f2bf(hi.w);
    *(int4*)dst = p.v;
}

// ---------------------------------------------------------------------------
// Fused GEMM (gates = A @ W'^T) + bias + activations + c/h epilogue.
// 256x256 tile, BK=64, 8 waves (2Mx4N), 512 threads. 8-phase schedule with
// counted vmcnt (T3+T4), setprio around MFMA clusters (T5), XCD-bijective
// block swizzle (T1).
//
// FRAGMENT-LINEAR LDS layout (replaces XOR swizzle, which had a 2-way
// conflict in every 8-lane phase -> 19.1M conflict cycles, MfmaUtil 33%):
// each k-half plane = [16 subtiles][1024B]; subtile s covers tile rows
// 16s..16s+15; within a subtile, byte l*16 holds (row 16s+(l&15),
// k-chunk l>>4) -- exactly lane l's MFMA fragment. Every ds_read_b128 is a
// contiguous wave-linear 1024B read: each 8-lane phase covers 128B
// contiguous = all 32 banks once. Zero conflicts by construction.
// Achieved per rule "both-sides-or-neither": LDS dest of global_load_lds
// stays linear; the per-lane GLOBAL source address carries the permutation
// (lane l of stage-wave w fetches A[m0+16w+(l&15)][k+(l>>4)*8]).
//
// Staging units per K-tile: (A,kh0)(B,kh0)(A,kh1)(B,kh1), 2 loads/thread
// each, issued one per phase for tile t+1 while computing tile t. vmcnt(4)
// at phases 1 and 3 retires exactly the 2 units the next phases need; 4
// loads always stay in flight across barriers (never drained in main loop).
// ---------------------------------------------------------------------------
__global__ __launch_bounds__(512, 2) void lstm_gemm(
    const unsigned short* __restrict__ A,   // [N_ROWS][K_DIM] bf16
    const unsigned short* __restrict__ W,   // [G_DIM][K_DIM]  bf16, interleaved
    const float* __restrict__ bperm,        // [G_DIM]
    const float* __restrict__ c_prev,       // [N_ROWS][F_DIM]
    float* __restrict__ out)                // [N_ROWS][F_DIM]
{
    extern __shared__ char smem[];          // 131072 bytes

    // XCD-aware bijective swizzle (1024 blocks, 1024%8==0). Row-blocks walk
    // fastest: each XCD chunk of 128 blocks = 2 W-panels (1.5 MB, L2-fits)
    // reused across 64 A row-blocks.
    const int bid = blockIdx.x;                   // 0..1023
    const int s   = (bid & 7) * 128 + (bid >> 3);
    const int m0  = (s & 63) << 8;                // row-block * 256
    const int n0  = (s >> 6) << 8;                // gate-block * 256

    const int tid  = threadIdx.x;
    const int lane = tid & 63;
    const int wave = tid >> 6;
    const int wmi  = wave >> 2;                   // 0..1
    const int wni  = wave & 3;                    // 0..3
    const int lrow = lane & 15;
    const int quad = lane >> 4;

    // fragment-linear read offsets within a 16 KiB k-half plane:
    // A subtile index = wmi*8 + mt, B subtile index = wni*4 + nt.
    const int afrag = wmi * 8192 + (lane << 4);   // + mt*1024
    const int bfrag = wni * 4096 + (lane << 4);   // + nt*1024

    // staging: lane l of wave w covers (row 16w+(l&15), k-chunk l>>4); the
    // second load of each unit covers rows +128. LDS dest linear per wave.
    const unsigned short* aS0 = A + (long)(m0 + wave * 16 + lrow) * K_DIM + quad * 8;
    const unsigned short* aS1 = aS0 + (long)128 * K_DIM;
    const unsigned short* wS0 = W + (long)(n0 + wave * 16 + lrow) * K_DIM + quad * 8;
    const unsigned short* wS1 = wS0 + (long)128 * K_DIM;
    const int du0 = wave * 1024;                  // subtile 'wave'
    const int du1 = du0 + 8192;                   // subtile 'wave+8'

    v4f acc[8][4] = {};                           // 128 fp32 accum / lane

    // plane index = BUF*2 + khalf; A planes at 0, B planes at +65536
    auto stageA = [&](int plane, int koff) {
        __builtin_amdgcn_global_load_lds((gptr1)(aS0 + koff),
                                         (lptr3)(smem + (plane << 14) + du0), 16, 0, 0);
        __builtin_amdgcn_global_load_lds((gptr1)(aS1 + koff),
                                         (lptr3)(smem + (plane << 14) + du1), 16, 0, 0);
    };
    auto stageB = [&](int plane, int koff) {
        __builtin_amdgcn_global_load_lds((gptr1)(wS0 + koff),
                                         (lptr3)(smem + 65536 + (plane << 14) + du0), 16, 0, 0);
        __builtin_amdgcn_global_load_lds((gptr1)(wS1 + koff),
                                         (lptr3)(smem + 65536 + (plane << 14) + du1), 16, 0, 0);
    };

#define MFMA_BLK(MB)                                                            \
    __builtin_amdgcn_s_setprio(1);                                              \
    _Pragma("unroll")                                                           \
    for (int mt = 0; mt < 4; ++mt)                                              \
        _Pragma("unroll")                                                       \
        for (int nt = 0; nt < 4; ++nt)                                          \
            acc[(MB)*4 + mt][nt] = __builtin_amdgcn_mfma_f32_16x16x32_bf16(     \
                afr[mt], bfr[nt], acc[(MB)*4 + mt][nt], 0, 0, 0);               \
    __builtin_amdgcn_s_setprio(0);

    // One K-tile = 4 phases. kn = k-element offset of the tile being prefetched.
    auto tile = [&](int BUF, int kn, auto pf_tag) {
        constexpr bool PF = decltype(pf_tag)::value;
        const char* A0p = smem + ((BUF * 2 + 0) << 14);
        const char* A1p = smem + ((BUF * 2 + 1) << 14);
        const char* B0p = A0p + 65536;
        const char* B1p = A1p + 65536;
        const int   pb  = (BUF ^ 1) * 2;
        v8bf afr[4], bfr[4];

        // ---- phase 0 : kh=0, mt 0-3 ----
#pragma unroll
        for (int nt = 0; nt < 4; ++nt) bfr[nt] = *(const v8bf*)(B0p + bfrag + nt * 1024);
#pragma unroll
        for (int mt = 0; mt < 4; ++mt) afr[mt] = *(const v8bf*)(A0p + afrag + mt * 1024);
        if constexpr (PF) stageA(pb + 0, kn);
        __builtin_amdgcn_s_barrier();
        asm volatile("s_waitcnt lgkmcnt(0)" ::: "memory");
        MFMA_BLK(0)
        __builtin_amdgcn_s_barrier();

        // ---- phase 1 : kh=0, mt 4-7 (reuse bfr) ----
#pragma unroll
        for (int mt = 0; mt < 4; ++mt) afr[mt] = *(const v8bf*)(A0p + afrag + (4 + mt) * 1024);
        if constexpr (PF) {
            stageB(pb + 0, kn);
            asm volatile("s_waitcnt vmcnt(4)" ::: "memory");  // lands (A,kh1)(B,kh1) of cur tile
        } else {
            asm volatile("s_waitcnt vmcnt(0)" ::: "memory");  // last tile: drain kh1
        }
        __builtin_amdgcn_s_barrier();
        asm volatile("s_waitcnt lgkmcnt(0)" ::: "memory");
        MFMA_BLK(1)
        __builtin_amdgcn_s_barrier();

        // ---- phase 2 : kh=1, mt 0-3 ----
#pragma unroll
        for (int nt = 0; nt < 4; ++nt) bfr[nt] = *(const v8bf*)(B1p + bfrag + nt * 1024);
#pragma unroll
        for (int mt = 0; mt < 4; ++mt) afr[mt] = *(const v8bf*)(A1p + afrag + mt * 1024);
        if constexpr (PF) stageA(pb + 1, kn + 32);
        __builtin_amdgcn_s_barrier();
        asm volatile("s_waitcnt lgkmcnt(0)" ::: "memory");
        MFMA_BLK(0)
        __builtin_amdgcn_s_barrier();

        // ---- phase 3 : kh=1, mt 4-7 ----
#pragma unroll
        for (int mt = 0; mt < 4; ++mt) afr[mt] = *(const v8bf*)(A1p + afrag + (4 + mt) * 1024);
        if constexpr (PF) {
            stageB(pb + 1, kn + 32);
            asm volatile("s_waitcnt vmcnt(4)" ::: "memory");  // lands (A,kh0)(B,kh0) of next tile
        }
        __builtin_amdgcn_s_barrier();
        asm volatile("s_waitcnt lgkmcnt(0)" ::: "memory");
        MFMA_BLK(1)
        __builtin_amdgcn_s_barrier();
    };

    // prologue: stage tile 0 fully; keep kh1 in flight (vmcnt(4), not 0)
    stageA(0, 0);  stageB(0, 0);
    stageA(1, 32); stageB(1, 32);
    asm volatile("s_waitcnt vmcnt(4)" ::: "memory");
    __builtin_amdgcn_s_barrier();

    int kn = 64;
    for (int t = 0; t < NT - 1; ++t) {
        tile(t & 1, kn, std::true_type{});
        kn += 64;
    }
    tile((NT - 1) & 1, 0, std::false_type{});
#undef MFMA_BLK

    // ---- stage c_prev tile (256 rows x 64 f-cols) into padded LDS, coalesced ----
    float* cbuf = (float*)smem;                   // [256][CB_STR] = 68 KB (reuse GEMM LDS)
    const int fbase = n0 >> 2;
#pragma unroll
    for (int i = 0; i < 8; ++i) {
        const int q  = i * 512 + tid;             // 0..4095 float4-chunks
        const int r  = q >> 4;
        const int c4 = (q & 15) << 2;
        *(float4*)&cbuf[r * CB_STR + c4] =
            *(const float4*)&c_prev[(long)(m0 + r) * F_DIM + fbase + c4];
    }
    __syncthreads();

    // ---- fused epilogue (in-register 4x4 gate transpose, LDS-staged c/h) ----
    const int l3 = lane & 3;
    const int fl = (lane >> 2) & 3;
#pragma unroll
    for (int nt = 0; nt < 4; ++nt) {
        const int   gcol = n0 + wni * 64 + nt * 16 + lrow;
        const float bias = bperm[gcol];
#pragma unroll
        for (int mt = 0; mt < 8; ++mt) {
            float a0 = acc[mt][nt][0] + bias;
            float a1 = acc[mt][nt][1] + bias;
            float a2 = acc[mt][nt][2] + bias;
            float a3 = acc[mt][nt][3] + bias;
            // 4x4 transpose across lane quads: stage 1 (xor 1, reg bit 0)
            float s0 = (lane & 1) ? a0 : a1;
            float s1 = (lane & 1) ? a2 : a3;
            float t0 = __shfl_xor(s0, 1, 64);
            float t1 = __shfl_xor(s1, 1, 64);
            if (lane & 1) { a0 = t0; a2 = t1; } else { a1 = t0; a3 = t1; }
            // stage 2 (xor 2, reg bit 1)
            s0 = (lane & 2) ? a0 : a2;
            s1 = (lane & 2) ? a1 : a3;
            t0 = __shfl_xor(s0, 2, 64);
            t1 = __shfl_xor(s1, 2, 64);
            if (lane & 2) { a0 = t0; a1 = t1; } else { a2 = t0; a3 = t1; }
            // a0..a3 = pre-activation i,f,g,o for (local row, local f-col)
            const float iv = sigmoidf_fast(a0);
            const float fv = sigmoidf_fast(a1);
            const float gv = tanhf_fast(a2);
            const float ov = sigmoidf_fast(a3);
            const int lr = wmi * 128 + mt * 16 + quad * 4 + l3;   // 0..255
            const int lc = wni * 16 + nt * 4 + fl;                // 0..63
            const float cp = cbuf[lr * CB_STR + lc];
            const float cv = fv * cp + iv * gv;
            cbuf[lr * CB_STR + lc] = ov * tanhf_fast(cv);         // same-lane cell, no race
        }
    }
    __syncthreads();

    // ---- coalesced h store ----
#pragma unroll
    for (int i = 0; i < 8; ++i) {
        const int q  = i * 512 + tid;
        const int r  = q >> 4;
        const int c4 = (q & 15) << 2;
        *(float4*)&out[(long)(m0 + r) * F_DIM + fbase + c4] =
            *(const float4*)&cbuf[r * CB_STR + c4];
    }
}

// ---------------------------------------------------------------------------
// Inputs (setup_inputs order): behavior, h_prev, c_prev, Wh, Wx, b  (all fp32)
// Output: h (N_ROWS x F_DIM fp32)
// Workspace: A bf16 48 MB | W' bf16 12 MB | b' 16 KB
// ---------------------------------------------------------------------------
extern "C" void kernel_launch(void* const* d_in, const int* in_sizes, int n_in,
                              void* d_out, int out_size, void* d_ws, size_t ws_size,
                              hipStream_t stream) {
    const float* behavior = (const float*)d_in[0];
    const float* h_prev   = (const float*)d_in[1];
    const float* c_prev   = (const float*)d_in[2];
    const float* Wh       = (const float*)d_in[3];
    const float* Wx       = (const float*)d_in[4];
    const float* b        = (const float*)d_in[5];
    float* out = (float*)d_out;

    unsigned short* A  = (unsigned short*)d_ws;
    unsigned short* W  = A + (size_t)N_ROWS * K_DIM;
    float*       bperm = (float*)(W + (size_t)G_DIM * K_DIM);

    // Raise dynamic-LDS cap (host-side attribute set; no stream ops, safe
    // under graph capture).
    hipFuncSetAttribute(reinterpret_cast<const void*>(lstm_gemm),
                        hipFuncAttributeMaxDynamicSharedMemorySize, 131072);

    pack_all<<<N_ROWS + G_DIM, 192, 0, stream>>>(behavior, h_prev, Wh, Wx, b, A, W, bperm);
    lstm_gemm<<<dim3((N_ROWS / 256) * (G_DIM / 256)), 512, 131072, stream>>>(A, W, bperm, c_prev, out);
}

// Round 4
// 418.787 us; speedup vs baseline: 1.0650x; 1.0650x over previous
//
#include <hip/hip_runtime.h>
#include <hip/hip_bf16.h>
#include <stdint.h>
#include <type_traits>

// Problem constants (reference: N=16384, F=1024, B=512)
#define N_ROWS 16384
#define F_DIM  1024
#define B_DIM  512
#define K_DIM  1536   // F + B
#define G_DIM  4096   // 4*F
#define NT     24     // K_DIM / 64 K-tiles
#define CB_STR 68     // padded fp32 stride for epilogue LDS tile

typedef __bf16 v8bf __attribute__((ext_vector_type(8)));
typedef float  v4f  __attribute__((ext_vector_type(4)));

typedef const void __attribute__((address_space(1)))* gptr1;
typedef void       __attribute__((address_space(3)))* lptr3;

__device__ __forceinline__ unsigned short f2bf(float x) {
    union { float f; unsigned int u; } c; c.f = x;
    unsigned int u = c.u;
    return (unsigned short)((u + 0x7FFFu + ((u >> 16) & 1u)) >> 16);  // RNE; inputs finite
}

__device__ __forceinline__ float sigmoidf_fast(float x) {
    return 1.f / (1.f + __expf(-x));
}
__device__ __forceinline__ float tanhf_fast(float x) {
    return 1.f - 2.f / (__expf(2.f * x) + 1.f);   // saturates correctly at +/-1
}

// ---------------------------------------------------------------------------
// Merged pack kernel:
//   blocks [0, N_ROWS)           : A = bf16([h_prev | behavior]) row-major
//   blocks [N_ROWS, N_ROWS+G_DIM): W' = bf16 gate-interleaved [Wh | Wx], b'
// ---------------------------------------------------------------------------
__global__ void pack_all(const float* __restrict__ behavior,
                         const float* __restrict__ h_prev,
                         const float* __restrict__ Wh,
                         const float* __restrict__ Wx,
                         const float* __restrict__ b,
                         unsigned short* __restrict__ A,
                         unsigned short* __restrict__ W,
                         float* __restrict__ bperm) {
    const int blk = blockIdx.x;
    const int col = threadIdx.x * 8;              // 0..1528, never straddles 1024
    const float* src;
    unsigned short* dst;
    if (blk < N_ROWS) {
        src = (col < F_DIM) ? h_prev + (long)blk * F_DIM + col
                            : behavior + (long)blk * B_DIM + (col - F_DIM);
        dst = A + (long)blk * K_DIM + col;
    } else {
        const int gp   = blk - N_ROWS;
        const int gate = gp & 3;
        const int f    = gp >> 2;
        const int g    = gate * F_DIM + f;        // original row in Wh/Wx
        src = (col < F_DIM) ? Wh + (long)g * F_DIM + col
                            : Wx + (long)g * B_DIM + (col - F_DIM);
        dst = W + (long)gp * K_DIM + col;
        if (threadIdx.x == 0) bperm[gp] = b[g];
    }
    float4 lo = *(const float4*)src;
    float4 hi = *(const float4*)(src + 4);
    union { unsigned short u[8]; int4 v; } p;
    p.u[0] = f2bf(lo.x); p.u[1] = f2bf(lo.y); p.u[2] = f2bf(lo.z); p.u[3] = f2bf(lo.w);
    p.u[4] = f2bf(hi.x); p.u[5] = f2bf(hi.y); p.u[6] = f2bf(hi.z); p.u[7] = f2bf(hi.w);
    *(int4*)dst = p.v;
}

// ---------------------------------------------------------------------------
// Fused GEMM (gates = A @ W'^T) + bias + activations + c/h epilogue.
// 256x256 tile, BK=64, 8 waves (2Mx4N), 512 threads, 4 phases/K-tile with
// counted stage pipeline (issue early, wait once/tile on old loads).
//
// LDS layout (128 KiB): A[2 buf][256 rows][128B] at 0, B same at +64KiB.
// 16B slot s of row r holds k-chunk s ^ (r&7)  (chunk-swizzle):
//  - staging: lane l covers row l>>3, chunk (l&7)^(l>>3) -> lanes 0-7 sweep
//    one row's contiguous 128B (quad=64B) => 8x128B segments per
//    global_load_lds, LDS dest linear (permutation lives in global source).
//  - fragment reads: addr = row*128 + (((kh*4+q) ^ (lrow&7))<<4); every
//    8-lane phase of ds_read_b128 covers all 32 banks exactly once.
//
// Staging: 4 A-units (64 rows each) issued at ph0, 4 B-units at ph1, for
// tile t+1 while computing tile t; single vmcnt(0) at ph3 retires loads
// issued 2-3 phases (~1500 cyc) earlier -> HBM latency fully covered.
// ---------------------------------------------------------------------------
__global__ __launch_bounds__(512, 2) void lstm_gemm(
    const unsigned short* __restrict__ A,   // [N_ROWS][K_DIM] bf16
    const unsigned short* __restrict__ W,   // [G_DIM][K_DIM]  bf16, interleaved
    const float* __restrict__ bperm,        // [G_DIM]
    const float* __restrict__ c_prev,       // [N_ROWS][F_DIM]
    float* __restrict__ out)                // [N_ROWS][F_DIM]
{
    extern __shared__ char smem[];          // 131072 bytes

    // Plain raster, n fastest: 16-block bands share the A panel; W' (12 MB)
    // is LLC-resident across bands (r0 evidence: 273 MB FETCH vs 438 swizzled).
    const int bid = blockIdx.x;                   // 0..1023
    const int n0  = (bid & 15) << 8;              // gate-block * 256
    const int m0  = (bid >> 4) << 8;              // row-block * 256

    const int tid  = threadIdx.x;
    const int lane = tid & 63;
    const int wave = tid >> 6;
    const int wmi  = wave >> 2;                   // 0..1
    const int wni  = wave & 3;                    // 0..3
    const int lrow = lane & 15;
    const int quad = lane >> 4;

    // fragment-read per-lane constants
    const int g7  = lrow & 7;
    const int cs0 = (quad ^ g7) << 4;             // kh0 slot offset (bytes)
    const int cs1 = ((4 + quad) ^ g7) << 4;       // kh1 slot offset
    const int aRd = wmi * 16384 + lrow * 128;     // + buf*32768 + mt*2048 + cs
    const int bRd = wni * 8192  + lrow * 128;     // + 65536 + buf*32768 + nt*2048 + cs

    // staging per-lane source bases: row l>>3, chunk (l&7)^(l>>3)
    const int srow = lane >> 3;
    const int schk = (lane & 7) ^ srow;
    const unsigned short* sA = A + (long)(m0 + wave * 8 + srow) * K_DIM + schk * 8;
    const unsigned short* sB = W + (long)(n0 + wave * 8 + srow) * K_DIM + schk * 8;
    const int sDst = wave * 1024;                 // + matrix base + buf*32768 + u*8192

    v4f acc[8][4] = {};                           // 128 fp32 accum / lane

    // stage one 256-row operand tile (4 units x 64 rows), LDS dest linear
    auto stage4 = [&](const unsigned short* src, int ldsbase, int koff) {
#pragma unroll
        for (int u = 0; u < 4; ++u)
            __builtin_amdgcn_global_load_lds(
                (gptr1)(src + (long)u * 64 * K_DIM + koff),
                (lptr3)(smem + ldsbase + u * 8192 + sDst), 16, 0, 0);
    };

#define MFMA_BLK(MB)                                                            \
    __builtin_amdgcn_s_setprio(1);                                              \
    _Pragma("unroll")                                                           \
    for (int mt = 0; mt < 4; ++mt)                                              \
        _Pragma("unroll")                                                       \
        for (int nt = 0; nt < 4; ++nt)                                          \
            acc[(MB)*4 + mt][nt] = __builtin_amdgcn_mfma_f32_16x16x32_bf16(     \
                afr[mt], bfr[nt], acc[(MB)*4 + mt][nt], 0, 0, 0);               \
    __builtin_amdgcn_s_setprio(0);

    // One K-tile = 4 phases; kn = k offset of the tile being prefetched.
    auto tile = [&](int BUF, int kn, auto pf_tag) {
        constexpr bool PF = decltype(pf_tag)::value;
        const int Ab = BUF * 32768;
        const int Bb = 65536 + Ab;
        const int Pb = (BUF ^ 1) * 32768;
        v8bf afr[4], bfr[4];

        // ---- phase 0 : kh0, mt 0-3 ----
#pragma unroll
        for (int nt = 0; nt < 4; ++nt) bfr[nt] = *(const v8bf*)(smem + Bb + bRd + nt * 2048 + cs0);
#pragma unroll
        for (int mt = 0; mt < 4; ++mt) afr[mt] = *(const v8bf*)(smem + Ab + aRd + mt * 2048 + cs0);
        if constexpr (PF) stage4(sA, Pb, kn);
        __builtin_amdgcn_s_barrier();
        asm volatile("s_waitcnt lgkmcnt(0)" ::: "memory");
        MFMA_BLK(0)
        __builtin_amdgcn_s_barrier();

        // ---- phase 1 : kh0, mt 4-7 (reuse bfr) ----
#pragma unroll
        for (int mt = 0; mt < 4; ++mt) afr[mt] = *(const v8bf*)(smem + Ab + aRd + (4 + mt) * 2048 + cs0);
        if constexpr (PF) stage4(sB, 65536 + Pb, kn);
        __builtin_amdgcn_s_barrier();
        asm volatile("s_waitcnt lgkmcnt(0)" ::: "memory");
        MFMA_BLK(1)
        __builtin_amdgcn_s_barrier();

        // ---- phase 2 : kh1, mt 0-3 ----
#pragma unroll
        for (int nt = 0; nt < 4; ++nt) bfr[nt] = *(const v8bf*)(smem + Bb + bRd + nt * 2048 + cs1);
#pragma unroll
        for (int mt = 0; mt < 4; ++mt) afr[mt] = *(const v8bf*)(smem + Ab + aRd + mt * 2048 + cs1);
        __builtin_amdgcn_s_barrier();
        asm volatile("s_waitcnt lgkmcnt(0)" ::: "memory");
        MFMA_BLK(0)
        __builtin_amdgcn_s_barrier();

        // ---- phase 3 : kh1, mt 4-7; retire this tile's prefetch (old loads) ----
#pragma unroll
        for (int mt = 0; mt < 4; ++mt) afr[mt] = *(const v8bf*)(smem + Ab + aRd + (4 + mt) * 2048 + cs1);
        asm volatile("s_waitcnt vmcnt(0)" ::: "memory");
        __builtin_amdgcn_s_barrier();
        asm volatile("s_waitcnt lgkmcnt(0)" ::: "memory");
        MFMA_BLK(1)
        __builtin_amdgcn_s_barrier();
    };

    // prologue: stage tile 0
    stage4(sA, 0, 0);
    stage4(sB, 65536, 0);
    asm volatile("s_waitcnt vmcnt(0)" ::: "memory");
    __builtin_amdgcn_s_barrier();

    int kn = 64;
    for (int t = 0; t < NT - 1; ++t) {
        tile(t & 1, kn, std::true_type{});
        kn += 64;
    }
    tile((NT - 1) & 1, 0, std::false_type{});
#undef MFMA_BLK

    // ---- stage c_prev tile (256 rows x 64 f-cols) into padded LDS, coalesced ----
    float* cbuf = (float*)smem;                   // [256][CB_STR] = 68 KB (reuse GEMM LDS)
    const int fbase = n0 >> 2;
#pragma unroll
    for (int i = 0; i < 8; ++i) {
        const int q  = i * 512 + tid;             // 0..4095 float4-chunks
        const int r  = q >> 4;
        const int c4 = (q & 15) << 2;
        *(float4*)&cbuf[r * CB_STR + c4] =
            *(const float4*)&c_prev[(long)(m0 + r) * F_DIM + fbase + c4];
    }
    __syncthreads();

    // ---- fused epilogue (in-register 4x4 gate transpose, LDS-staged c/h) ----
    const int l3 = lane & 3;
    const int fl = (lane >> 2) & 3;
#pragma unroll
    for (int nt = 0; nt < 4; ++nt) {
        const int   gcol = n0 + wni * 64 + nt * 16 + lrow;
        const float bias = bperm[gcol];
#pragma unroll
        for (int mt = 0; mt < 8; ++mt) {
            float a0 = acc[mt][nt][0] + bias;
            float a1 = acc[mt][nt][1] + bias;
            float a2 = acc[mt][nt][2] + bias;
            float a3 = acc[mt][nt][3] + bias;
            // 4x4 transpose across lane quads: stage 1 (xor 1, reg bit 0)
            float s0 = (lane & 1) ? a0 : a1;
            float s1 = (lane & 1) ? a2 : a3;
            float t0 = __shfl_xor(s0, 1, 64);
            float t1 = __shfl_xor(s1, 1, 64);
            if (lane & 1) { a0 = t0; a2 = t1; } else { a1 = t0; a3 = t1; }
            // stage 2 (xor 2, reg bit 1)
            s0 = (lane & 2) ? a0 : a2;
            s1 = (lane & 2) ? a1 : a3;
            t0 = __shfl_xor(s0, 2, 64);
            t1 = __shfl_xor(s1, 2, 64);
            if (lane & 2) { a0 = t0; a1 = t1; } else { a2 = t0; a3 = t1; }
            // a0..a3 = pre-activation i,f,g,o for (local row, local f-col)
            const float iv = sigmoidf_fast(a0);
            const float fv = sigmoidf_fast(a1);
            const float gv = tanhf_fast(a2);
            const float ov = sigmoidf_fast(a3);
            const int lr = wmi * 128 + mt * 16 + quad * 4 + l3;   // 0..255
            const int lc = wni * 16 + nt * 4 + fl;                // 0..63
            const float cp = cbuf[lr * CB_STR + lc];
            const float cv = fv * cp + iv * gv;
            cbuf[lr * CB_STR + lc] = ov * tanhf_fast(cv);         // same-lane cell, no race
        }
    }
    __syncthreads();

    // ---- coalesced h store ----
#pragma unroll
    for (int i = 0; i < 8; ++i) {
        const int q  = i * 512 + tid;
        const int r  = q >> 4;
        const int c4 = (q & 15) << 2;
        *(float4*)&out[(long)(m0 + r) * F_DIM + fbase + c4] =
            *(const float4*)&cbuf[r * CB_STR + c4];
    }
}

// ---------------------------------------------------------------------------
// Inputs (setup_inputs order): behavior, h_prev, c_prev, Wh, Wx, b  (all fp32)
// Output: h (N_ROWS x F_DIM fp32)
// Workspace: A bf16 48 MB | W' bf16 12 MB | b' 16 KB
// ---------------------------------------------------------------------------
extern "C" void kernel_launch(void* const* d_in, const int* in_sizes, int n_in,
                              void* d_out, int out_size, void* d_ws, size_t ws_size,
                              hipStream_t stream) {
    const float* behavior = (const float*)d_in[0];
    const float* h_prev   = (const float*)d_in[1];
    const float* c_prev   = (const float*)d_in[2];
    const float* Wh       = (const float*)d_in[3];
    const float* Wx       = (const float*)d_in[4];
    const float* b        = (const float*)d_in[5];
    float* out = (float*)d_out;

    unsigned short* A  = (unsigned short*)d_ws;
    unsigned short* W  = A + (size_t)N_ROWS * K_DIM;
    float*       bperm = (float*)(W + (size_t)G_DIM * K_DIM);

    hipFuncSetAttribute(reinterpret_cast<const void*>(lstm_gemm),
                        hipFuncAttributeMaxDynamicSharedMemorySize, 131072);

    pack_all<<<N_ROWS + G_DIM, 192, 0, stream>>>(behavior, h_prev, Wh, Wx, b, A, W, bperm);
    lstm_gemm<<<dim3((N_ROWS / 256) * (G_DIM / 256)), 512, 131072, stream>>>(A, W, bperm, c_prev, out);
}